// Round 2
// baseline (487.379 us; speedup 1.0000x reference)
//
#include <hip/hip_runtime.h>
#include <hip/hip_bf16.h>

// RGCN 2-layer forward. N=50000 nodes, H=16 hidden, R=32 relations, C=8
// classes, E=1.6M edges. Output [N, C] log-softmax.
//
// Input float dtype is ambiguous (harness may deliver bf16 or fp32); a
// runtime sniff kernel inspects w1's bit patterns and sets a flag that all
// kernels branch on (wave-uniform branch, negligible cost). Output dtype
// follows the same flag.

constexpr int Nn = 50000;
constexpr int Hh = 16;
constexpr int Rr = 32;
constexpr int Cc = 8;
constexpr int Ee = 1600000;

__device__ __forceinline__ float b2f(__hip_bfloat16 v) { return __bfloat162float(v); }

// --- 0. dtype sniff: even uint16 half-words of w1 -----------------------------
// bf16 data: each even half-word is a real N(0,0.05) bf16 -> exponent field in
// ~[113,125] almost surely. fp32 data: even half-words are low mantissa bits
// -> exponent field uniform over 0..255 (~12% in range). 64 samples, thresh 32.
__global__ void sniff_kernel(const unsigned short* __restrict__ w, int* __restrict__ flag) {
    if (blockIdx.x == 0 && threadIdx.x == 0) {
        int hits = 0;
        for (int i = 0; i < 64; ++i) {
            unsigned short u = w[2 * i];
            int e = (u >> 7) & 0xFF;
            if (e >= 100 && e <= 130) ++hits;
        }
        *flag = (hits >= 32) ? 1 : 0;   // 1 = bf16, 0 = fp32
    }
}

// --- 1. count edges per (relation, dst) segment -------------------------------
__global__ void count_kernel(const int* __restrict__ et, const int* __restrict__ dst,
                             int* __restrict__ cnt) {
    int e = blockIdx.x * blockDim.x + threadIdx.x;
    if (e < Ee) atomicAdd(&cnt[et[e] * Nn + dst[e]], 1);
}

// --- 2. cnt -> 1/max(cnt,1) in place ------------------------------------------
__global__ void inv_kernel(float* __restrict__ cnt) {
    int i = blockIdx.x * blockDim.x + threadIdx.x;
    if (i < Rr * Nn) {
        int c = ((int*)cnt)[i];
        cnt[i] = (c > 0) ? 1.0f / (float)c : 0.0f;
    }
}

// --- 3. layer-1 scatter: x_sum[dst] += w1[rel, src] / cnt[rel, dst] -----------
// 8 lanes per edge, each lane handles 2 features.
__global__ void l1_kernel(const int* __restrict__ src, const int* __restrict__ dst,
                          const int* __restrict__ et,
                          const void* __restrict__ w1,
                          const float* __restrict__ inv_cnt,
                          const int* __restrict__ flag,
                          float* __restrict__ x) {
    int t = blockIdx.x * blockDim.x + threadIdx.x;
    if (t >= Ee * 8) return;
    int e = t >> 3, lane = t & 7;
    int rel = et[e], s = src[e], d = dst[e];
    float inv = inv_cnt[rel * Nn + d];
    size_t row = (size_t)(rel * Nn + s) * Hh;
    float f0, f1;
    if (*flag) {
        __hip_bfloat162 v = ((const __hip_bfloat162*)((const __hip_bfloat16*)w1 + row))[lane];
        f0 = __low2float(v); f1 = __high2float(v);
    } else {
        float2 v = ((const float2*)((const float*)w1 + row))[lane];
        f0 = v.x; f1 = v.y;
    }
    atomicAdd(&x[d * Hh + lane * 2 + 0], f0 * inv);
    atomicAdd(&x[d * Hh + lane * 2 + 1], f1 * inv);
}

// --- 4. x = relu(x_sum + root1 + b1) ------------------------------------------
__global__ void relu_kernel(float* __restrict__ x,
                            const void* __restrict__ root1,
                            const void* __restrict__ b1,
                            const int* __restrict__ flag) {
    int i = blockIdx.x * blockDim.x + threadIdx.x;
    if (i < Nn * Hh) {
        float r, b;
        if (*flag) {
            r = b2f(((const __hip_bfloat16*)root1)[i]);
            b = b2f(((const __hip_bfloat16*)b1)[i & (Hh - 1)]);
        } else {
            r = ((const float*)root1)[i];
            b = ((const float*)b1)[i & (Hh - 1)];
        }
        float v = x[i] + r + b;
        x[i] = v > 0.0f ? v : 0.0f;
    }
}

// --- 5. layer-2 scatter: out_acc[dst,c] += (x[src] . w2[rel,:,c]) / cnt -------
// 8 lanes per edge, one per output class.
__global__ void l2_kernel(const int* __restrict__ src, const int* __restrict__ dst,
                          const int* __restrict__ et,
                          const float* __restrict__ x,
                          const void* __restrict__ w2,
                          const float* __restrict__ inv_cnt,
                          const int* __restrict__ flag,
                          float* __restrict__ oacc) {
    int t = blockIdx.x * blockDim.x + threadIdx.x;
    if (t >= Ee * Cc) return;
    int e = t >> 3, c = t & 7;
    int rel = et[e], s = src[e], d = dst[e];
    float inv = inv_cnt[rel * Nn + d];
    const float* xp = x + s * Hh;
    float acc = 0.0f;
    if (*flag) {
        const __hip_bfloat16* wp = (const __hip_bfloat16*)w2 + rel * (Hh * Cc) + c;
#pragma unroll
        for (int h = 0; h < Hh; ++h) acc += xp[h] * b2f(wp[h * Cc]);
    } else {
        const float* wp = (const float*)w2 + rel * (Hh * Cc) + c;
#pragma unroll
        for (int h = 0; h < Hh; ++h) acc += xp[h] * wp[h * Cc];
    }
    atomicAdd(&oacc[d * Cc + c], acc * inv);
}

// --- 6. epilogue: out = log_softmax(out_acc + x @ root2 + b2) -----------------
__global__ void out_kernel(const float* __restrict__ x, const float* __restrict__ oacc,
                           const void* __restrict__ root2,
                           const void* __restrict__ b2v,
                           const int* __restrict__ flag,
                           void* __restrict__ out) {
    int n = blockIdx.x * blockDim.x + threadIdx.x;
    if (n >= Nn) return;
    int isbf = *flag;
    float xv[Hh];
#pragma unroll
    for (int h = 0; h < Hh; ++h) xv[h] = x[n * Hh + h];
    float v[Cc];
#pragma unroll
    for (int c = 0; c < Cc; ++c) {
        float acc = oacc[n * Cc + c];
        acc += isbf ? b2f(((const __hip_bfloat16*)b2v)[c]) : ((const float*)b2v)[c];
#pragma unroll
        for (int h = 0; h < Hh; ++h) {
            float w = isbf ? b2f(((const __hip_bfloat16*)root2)[h * Cc + c])
                           : ((const float*)root2)[h * Cc + c];
            acc += xv[h] * w;
        }
        v[c] = acc;
    }
    float m = v[0];
#pragma unroll
    for (int c = 1; c < Cc; ++c) m = fmaxf(m, v[c]);
    float sum = 0.0f;
#pragma unroll
    for (int c = 0; c < Cc; ++c) sum += expf(v[c] - m);
    float lse = m + logf(sum);
    if (isbf) {
        __hip_bfloat16* o = (__hip_bfloat16*)out;
#pragma unroll
        for (int c = 0; c < Cc; ++c) o[n * Cc + c] = __float2bfloat16(v[c] - lse);
    } else {
        float* o = (float*)out;
#pragma unroll
        for (int c = 0; c < Cc; ++c) o[n * Cc + c] = v[c] - lse;
    }
}

extern "C" void kernel_launch(void* const* d_in, const int* in_sizes, int n_in,
                              void* d_out, int out_size, void* d_ws, size_t ws_size,
                              hipStream_t stream) {
    const int* edge_index = (const int*)d_in[0];     // [2, E]
    const int* src = edge_index;
    const int* dst = edge_index + Ee;
    const int* et  = (const int*)d_in[1];            // [E]
    const void* w1    = d_in[2];  // [R,N,H]
    const void* root1 = d_in[3];  // [N,H]
    const void* b1    = d_in[4];  // [H]
    const void* w2    = d_in[5];  // [R,H,C]
    const void* root2 = d_in[6];  // [H,C]
    const void* b2    = d_in[7];  // [C]

    // workspace layout (fp32): inv_cnt [R*N] | x [N*H] | out_acc [N*C] | flag [1]
    float* inv_cnt = (float*)d_ws;
    float* x       = inv_cnt + (size_t)Rr * Nn;
    float* oacc    = x + (size_t)Nn * Hh;
    int*   flag    = (int*)(oacc + (size_t)Nn * Cc);
    size_t zero_bytes = ((size_t)Rr * Nn + (size_t)Nn * Hh + (size_t)Nn * Cc) * sizeof(float);
    hipMemsetAsync(d_ws, 0, zero_bytes, stream);

    sniff_kernel<<<1, 64, 0, stream>>>((const unsigned short*)w1, flag);
    count_kernel<<<(Ee + 255) / 256, 256, 0, stream>>>(et, dst, (int*)inv_cnt);
    inv_kernel<<<(Rr * Nn + 255) / 256, 256, 0, stream>>>(inv_cnt);
    l1_kernel<<<(Ee * 8 + 255) / 256, 256, 0, stream>>>(src, dst, et, w1, inv_cnt, flag, x);
    relu_kernel<<<(Nn * Hh + 255) / 256, 256, 0, stream>>>(x, root1, b1, flag);
    l2_kernel<<<(Ee * Cc + 255) / 256, 256, 0, stream>>>(src, dst, et, x, w2, inv_cnt, flag, oacc);
    out_kernel<<<(Nn + 255) / 256, 256, 0, stream>>>(x, oacc, root2, b2, flag, d_out);
}